// Round 2
// baseline (152.152 us; speedup 1.0000x reference)
//
#include <hip/hip_runtime.h>

// SA neuron forward scan: B=16, T=2000, F=1024.
// out[0 .. B*(T+1)*F)               = imem_trace (float32)
// out[B*(T+1)*F .. 2*B*(T+1)*F)     = spikes (written as 0.0f/1.0f)
//
// Per-chain recurrence (constants folded, fp32, within 2%-of-maxabs tol):
//   i_net = x*1e-12 - i_ahp - i_ref
//   z     = fma(z, 0.99, 0.05*i_net);  fired = z >= 2.5e-9;  z = fired?0:z
//   i_ahp = fma(i_ahp, 0.984, fired?1.66e-11:0)
//   i_ref = fma(i_ref, -0.6,  fired?1.6e-9 :0)
//   imem[t+1] = z*332;  spk[t] = fired;  spk[T] = fired_{T-1};  imem[0]=0

namespace {
constexpr int Bb = 16;
constexpr int Tt = 2000;
constexpr int Ff = 1024;
constexpr int TS = 20;        // timesteps per LDS tile (multiple of 4)
constexpr int NT = Tt / TS;   // 100 tiles (even)

constexpr float C_SCALE = 1e-12f;   // CURRENT_SCALE
constexpr float AZ      = 0.99f;    // 1 - DT_S*ONE_MINUS_A/TAU_M
constexpr float BZ      = 0.05f;    // DT_S/TAU_M
constexpr float CAHP    = 0.984f;   // 1 - DT_S/TAU_AHP
constexpr float CREF    = -0.6f;    // 1 - DT_S/TAU_REF
constexpr float ZTH     = 2.5e-9f;  // I_IN_OP/(1-A_FRAC)
constexpr float RR      = 332.0f;   // I_TH/I_TAU
constexpr float ITHAHP  = 1.66e-11f;
constexpr float ITAUREF = 1.6e-9f;
}  // namespace

__global__ __launch_bounds__(64, 1) void sa_scan(const float* __restrict__ in,
                                                 float* __restrict__ out) {
  const int lane = threadIdx.x;          // 0..63  -> f within block
  const int blk  = blockIdx.x;           // 0..255
  const int b    = blk >> 4;             // batch
  const int f0   = (blk & 15) << 6;      // feature base (64 per block)

  __shared__ float lds0[TS * 64];
  __shared__ float lds1[TS * 64];

  // Per-lane global source for global_load_lds staging:
  // instr j of a tile covers rows t0+4j..t0+4j+3; lane l -> row +(l>>4),
  // cols f0+(l&15)*4 .. +3 (16B). LDS dest offset = lane*16 bytes (linear).
  const float* gin =
      in + ((size_t)b * Tt + (lane >> 4)) * Ff + f0 + ((lane & 15) << 2);

  float* imem_p = out + ((size_t)b * (Tt + 1) + 1) * Ff + f0 + lane;  // row t+1
  float* spk_p =
      out + ((size_t)(Bb + b)) * (size_t)(Tt + 1) * Ff + f0 + lane;   // row t

  imem_p[-Ff] = 0.0f;  // imem_trace[:,0,:] = 0

  // `tile` is the TILE index; timestep base is tile*TS.  (R1 fix: was
  // interpreting the argument directly as a timestep base.)
  auto stage = [&](int tile, float* ldsbuf) {
    const size_t t0 = (size_t)tile * TS;
#pragma unroll
    for (int j = 0; j < TS / 4; ++j) {
      __builtin_amdgcn_global_load_lds(
          (const __attribute__((address_space(1))) void*)(gin + (t0 + 4 * j) * Ff),
          (__attribute__((address_space(3))) void*)(ldsbuf + j * 256),
          16, 0, 0);
    }
  };

  float z = 0.0f, i_ahp = 0.0f, i_ref = 0.0f, lastspk = 0.0f;

  auto compute = [&](const float* lb) {
#pragma unroll
    for (int tt = 0; tt < TS; ++tt) {
      float x = lb[tt * 64 + lane];
      float s = i_ahp + i_ref;
      float i_net = fmaf(x, C_SCALE, -s);
      z = fmaf(z, AZ, BZ * i_net);
      bool fired = z >= ZTH;
      z = fired ? 0.0f : z;
      lastspk = fired ? 1.0f : 0.0f;
      i_ahp = fmaf(i_ahp, CAHP, fired ? ITHAHP : 0.0f);
      i_ref = fmaf(i_ref, CREF, fired ? ITAUREF : 0.0f);
      imem_p[0] = z * RR;
      spk_p[0] = lastspk;
      imem_p += Ff;
      spk_p += Ff;
    }
  };

  // Prologue: stage tile 0, wait for it.
  stage(0, lds0);
  asm volatile("s_waitcnt vmcnt(0)" ::: "memory");

  // Main loop: double-buffered. Counted waits rely on issue order
  // (5 loads, then 40 stores); vmcnt(40) leaves only the 40 just-issued
  // stores outstanding => the 5 staging loads have retired.
  for (int k = 0; k < NT; k += 2) {
    stage(k + 1, lds1);                       // 5 loads in flight
    asm volatile("" ::: "memory");
    compute(lds0);                            // 40 stores
    asm volatile("s_waitcnt vmcnt(40)" ::: "memory");  // lds1 loads retired

    if (k + 2 < NT) stage(k + 2, lds0);
    asm volatile("" ::: "memory");
    compute(lds1);
    asm volatile("s_waitcnt vmcnt(40)" ::: "memory");  // lds0 loads retired
  }

  // spikes[:, T, :] = fired_{T-1}
  spk_p[0] = lastspk;
}

extern "C" void kernel_launch(void* const* d_in, const int* in_sizes, int n_in,
                              void* d_out, int out_size, void* d_ws,
                              size_t ws_size, hipStream_t stream) {
  const float* in = (const float*)d_in[0];
  float* out = (float*)d_out;
  dim3 grid(Bb * (Ff / 64));  // 256 blocks, 1 wave each
  dim3 block(64);
  hipLaunchKernelGGL(sa_scan, grid, block, 0, stream, in, out);
}

// Round 3
// 135.464 us; speedup vs baseline: 1.1232x; 1.1232x over previous
//
#include <hip/hip_runtime.h>

// SA neuron forward scan: B=16, T=2000, F=1024.
// out[0 .. B*(T+1)*F)               = imem_trace (float32)
// out[B*(T+1)*F .. 2*B*(T+1)*F)     = spikes (written as 0.0f/1.0f)
//
// R3: register-staged double buffer (no LDS). R2's global_load_lds + ds_read
// forced a compiler-inserted vmcnt(0) drain every tile (VALUBusy 7%, 26% HBM).
// Register prefetch gets counted vmcnt waits from the compiler instead.

namespace {
constexpr int Bb = 16;
constexpr int Tt = 2000;
constexpr int Ff = 1024;
constexpr int TS = 20;        // timesteps per register tile
constexpr int NT = Tt / TS;   // 100 tiles (even)

constexpr float C_SCALE = 1e-12f;   // CURRENT_SCALE
constexpr float AZ      = 0.99f;    // 1 - DT_S*ONE_MINUS_A/TAU_M
constexpr float BZ      = 0.05f;    // DT_S/TAU_M
constexpr float CAHP    = 0.984f;   // 1 - DT_S/TAU_AHP
constexpr float CREF    = -0.6f;    // 1 - DT_S/TAU_REF
constexpr float ZTH     = 2.5e-9f;  // I_IN_OP/(1-A_FRAC)
constexpr float RR      = 332.0f;   // I_TH/I_TAU
constexpr float ITHAHP  = 1.66e-11f;
constexpr float ITAUREF = 1.6e-9f;
}  // namespace

__global__ __launch_bounds__(64, 1) void sa_scan(const float* __restrict__ in,
                                                 float* __restrict__ out) {
  const int lane = threadIdx.x;          // 0..63  -> f within block
  const int blk  = blockIdx.x;           // 0..255
  const int b    = blk >> 4;             // batch
  const int f0   = (blk & 15) << 6;      // feature base (64 per block)

  // Per-lane input column: x[t] = gx[t*Ff]; 64 lanes -> 256B/row coalesced.
  const float* gx = in + (size_t)b * Tt * Ff + f0 + lane;

  float* imem_p = out + ((size_t)b * (Tt + 1) + 1) * Ff + f0 + lane;  // row t+1
  float* spk_p =
      out + ((size_t)(Bb + b)) * (size_t)(Tt + 1) * Ff + f0 + lane;   // row t

  imem_p[-Ff] = 0.0f;  // imem_trace[:,0,:] = 0

  float bufA[TS], bufB[TS];  // statically indexed only (full unroll)
  float z = 0.0f, i_ahp = 0.0f, i_ref = 0.0f, lastspk = 0.0f;

  // Prologue: tile 0 -> bufA.
#pragma unroll
  for (int j = 0; j < TS; ++j) bufA[j] = gx[(size_t)j * Ff];

#define SA_STEP(xval)                                   \
  {                                                     \
    float x = (xval);                                   \
    float s = i_ahp + i_ref;                            \
    float i_net = fmaf(x, C_SCALE, -s);                 \
    z = fmaf(z, AZ, BZ * i_net);                        \
    bool fired = z >= ZTH;                              \
    z = fired ? 0.0f : z;                               \
    lastspk = fired ? 1.0f : 0.0f;                      \
    i_ahp = fmaf(i_ahp, CAHP, fired ? ITHAHP : 0.0f);   \
    i_ref = fmaf(i_ref, CREF, fired ? ITAUREF : 0.0f);  \
    imem_p[0] = z * RR;                                 \
    spk_p[0] = lastspk;                                 \
    imem_p += Ff;                                       \
    spk_p += Ff;                                        \
  }

  for (int k = 0; k < NT; k += 2) {
    // Prefetch tile k+1 -> bufB (issued before compute; used next half-iter).
#pragma unroll
    for (int j = 0; j < TS; ++j)
      bufB[j] = gx[((size_t)(k + 1) * TS + j) * Ff];
#pragma unroll
    for (int tt = 0; tt < TS; ++tt) SA_STEP(bufA[tt]);

    if (k + 2 < NT) {
#pragma unroll
      for (int j = 0; j < TS; ++j)
        bufA[j] = gx[((size_t)(k + 2) * TS + j) * Ff];
    }
#pragma unroll
    for (int tt = 0; tt < TS; ++tt) SA_STEP(bufB[tt]);
  }

  // spikes[:, T, :] = fired_{T-1}
  spk_p[0] = lastspk;
#undef SA_STEP
}

extern "C" void kernel_launch(void* const* d_in, const int* in_sizes, int n_in,
                              void* d_out, int out_size, void* d_ws,
                              size_t ws_size, hipStream_t stream) {
  const float* in = (const float*)d_in[0];
  float* out = (float*)d_out;
  dim3 grid(Bb * (Ff / 64));  // 256 blocks, 1 wave each
  dim3 block(64);
  hipLaunchKernelGGL(sa_scan, grid, block, 0, stream, in, out);
}

// Round 4
// 88.780 us; speedup vs baseline: 1.7138x; 1.5258x over previous
//
#include <hip/hip_runtime.h>

// SA neuron forward scan: B=16, T=2000, F=1024.
// out[0 .. B*(T+1)*F)               = imem_trace (float32)
// out[B*(T+1)*F .. 2*B*(T+1)*F)     = spikes (written as 0.0f/1.0f)
//
// R4: T-chunked with decay halo. R3 was per-wave latency-bound (162 cy/step,
// VALUBusy ~6%) at 1 wave/CU. Split T into 8 chunks of 250 with a 500-step
// state-only warm-up (z decays 0.99^500 = e^-5 -> truncation ~4e-12, under
// the 1.29e-11 threshold; chunks 0-2 exact). 2048 waves = 8/CU -> TLP hides
// VMEM latency. State tracked in y = z*R space (one less mul/step).

namespace {
constexpr int Bb = 16;
constexpr int Tt = 2000;
constexpr int Ff = 1024;
constexpr int CH = 8;          // time chunks
constexpr int Lc = Tt / CH;    // 250 steps per chunk
constexpr int TS = 25;         // steps per register tile
constexpr int OT = Lc / TS;    // 10 output tiles (even)
constexpr int HALO = 500;      // warm-up steps (multiple of 2*TS)

// y = z*R space constants
constexpr float AZ  = 0.99f;               // z decay
constexpr float KIN = 1.66e-11f;           // BZ*R*CURRENT_SCALE = 0.05*332*1e-12
constexpr float CAHP = 0.984f;
constexpr float KA  = 2.7556e-10f;         // BZ*R*I_TH_AHP = 16.6*1.66e-11
constexpr float CREF = -0.6f;
constexpr float KR  = 2.656e-8f;           // BZ*R*I_TAU_REF = 16.6*1.6e-9
constexpr float YTH = 8.3e-7f;             // Z_TH*R = 2.5e-9*332
}  // namespace

__global__ __launch_bounds__(64, 2) void sa_scan(const float* __restrict__ in,
                                                 float* __restrict__ out) {
  const int lane = threadIdx.x;        // 0..63
  const int blk  = blockIdx.x;         // 0..2047
  const int c    = blk >> 8;           // time chunk 0..7
  const int g    = blk & 255;          // chain group
  const int b    = g >> 4;             // batch
  const int f0   = (g & 15) << 6;      // feature base

  // Per-lane input column: x[t] = gx[t*Ff]; wave reads 256B/row coalesced.
  const float* gx = in + (size_t)b * Tt * Ff + f0 + lane;

  const int t_out = c * Lc;                      // first output step
  const int t_h   = (t_out > HALO) ? t_out - HALO : 0;  // sim start (exact for c<=2)
  const int nh    = (t_out - t_h) / TS;          // halo tiles: 0, 10, or 20 (even)

  float* imem_p = out + ((size_t)b * (Tt + 1) + t_out + 1) * Ff + f0 + lane;
  float* spk_p =
      out + ((size_t)(Bb + b)) * (size_t)(Tt + 1) * Ff + (size_t)t_out * Ff +
      f0 + lane;

  if (c == 0) imem_p[-Ff] = 0.0f;  // imem_trace[:,0,:] = 0

  float A[TS], B[TS];  // statically indexed only (full unroll)
  float y = 0.0f, iA = 0.0f, iR = 0.0f, lastspk = 0.0f;

#define LOADT(buf, ti)                                        \
  {                                                           \
    const float* p = gx + (size_t)(t_h + (ti) * TS) * Ff;     \
    _Pragma("unroll") for (int j = 0; j < TS; ++j)            \
        buf[j] = p[(size_t)j * Ff];                           \
  }

#define HSTEP(xval)                                  \
  {                                                  \
    float x = (xval);                                \
    float inet = fmaf(x, KIN, -(iA + iR));           \
    y = fmaf(y, AZ, inet);                           \
    bool fired = y >= YTH;                           \
    y = fired ? 0.0f : y;                            \
    iA = fmaf(iA, CAHP, fired ? KA : 0.0f);          \
    iR = fmaf(iR, CREF, fired ? KR : 0.0f);          \
  }

#define FSTEP(xval)                                  \
  {                                                  \
    float x = (xval);                                \
    float inet = fmaf(x, KIN, -(iA + iR));           \
    y = fmaf(y, AZ, inet);                           \
    bool fired = y >= YTH;                           \
    y = fired ? 0.0f : y;                            \
    lastspk = fired ? 1.0f : 0.0f;                   \
    iA = fmaf(iA, CAHP, fired ? KA : 0.0f);          \
    iR = fmaf(iR, CREF, fired ? KR : 0.0f);          \
    imem_p[0] = y;                                   \
    spk_p[0] = lastspk;                              \
    imem_p += Ff;                                    \
    spk_p += Ff;                                     \
  }

  // Prologue: tile 0 -> A.
  LOADT(A, 0);

  // Halo: state-only, double-buffered pairs. After loop, A holds tile nh.
  for (int i = 0; i < nh; i += 2) {
    LOADT(B, i + 1);
#pragma unroll
    for (int j = 0; j < TS; ++j) HSTEP(A[j]);
    LOADT(A, i + 2);
#pragma unroll
    for (int j = 0; j < TS; ++j) HSTEP(B[j]);
  }

  // Output tiles nh .. nh+OT-1.
  for (int i = nh; i < nh + OT; i += 2) {
    LOADT(B, i + 1);
#pragma unroll
    for (int j = 0; j < TS; ++j) FSTEP(A[j]);
    if (i + 2 < nh + OT) LOADT(A, i + 2);
#pragma unroll
    for (int j = 0; j < TS; ++j) FSTEP(B[j]);
  }

  // spikes[:, T, :] = fired_{T-1} (last chunk owns row T)
  if (c == CH - 1) spk_p[0] = lastspk;

#undef LOADT
#undef HSTEP
#undef FSTEP
}

extern "C" void kernel_launch(void* const* d_in, const int* in_sizes, int n_in,
                              void* d_out, int out_size, void* d_ws,
                              size_t ws_size, hipStream_t stream) {
  const float* in = (const float*)d_in[0];
  float* out = (float*)d_out;
  dim3 grid(CH * Bb * (Ff / 64));  // 2048 blocks, 1 wave each, 8/CU
  dim3 block(64);
  hipLaunchKernelGGL(sa_scan, grid, block, 0, stream, in, out);
}

// Round 5
// 87.736 us; speedup vs baseline: 1.7342x; 1.0119x over previous
//
#include <hip/hip_runtime.h>

// SA neuron forward scan: B=16, T=2000, F=1024.
// out[0 .. B*(T+1)*F)               = imem_trace (float32)
// out[B*(T+1)*F .. 2*B*(T+1)*F)     = spikes (written as 0.0f/1.0f)
//
// R5: CH=10 (10 waves/CU) + nontemporal output stores.
// R4 analysis: per-CU store fair-share = 1 wave-store/22.5cy; 2 stores/step
// * 8 waves = ~360 cy/wave-step == observed 325. At 67% of mixed-BW roofline
// the residual is read-latency bubbles -> more TLP + keep L2/L3 clean of
// write data (outputs are never re-read).

namespace {
constexpr int Bb = 16;
constexpr int Tt = 2000;
constexpr int Ff = 1024;
constexpr int CH = 10;         // time chunks
constexpr int Lc = Tt / CH;    // 200 steps per chunk
constexpr int TS = 25;         // steps per register tile
constexpr int OT = Lc / TS;    // 8 output tiles (even)
constexpr int HALO = 500;      // warm-up steps; nh in {0,8,16,20} (even)

// y = z*R space constants
constexpr float AZ  = 0.99f;               // z decay
constexpr float KIN = 1.66e-11f;           // BZ*R*CURRENT_SCALE
constexpr float CAHP = 0.984f;
constexpr float KA  = 2.7556e-10f;         // BZ*R*I_TH_AHP
constexpr float CREF = -0.6f;
constexpr float KR  = 2.656e-8f;           // BZ*R*I_TAU_REF
constexpr float YTH = 8.3e-7f;             // Z_TH*R
}  // namespace

__global__ __launch_bounds__(64, 2) void sa_scan(const float* __restrict__ in,
                                                 float* __restrict__ out) {
  const int lane = threadIdx.x;        // 0..63
  const int blk  = blockIdx.x;         // 0..2559
  const int c    = blk >> 8;           // time chunk 0..9
  const int g    = blk & 255;          // chain group
  const int b    = g >> 4;             // batch
  const int f0   = (g & 15) << 6;      // feature base

  // Per-lane input column: x[t] = gx[t*Ff]; wave reads 256B/row coalesced.
  const float* gx = in + (size_t)b * Tt * Ff + f0 + lane;

  const int t_out = c * Lc;                             // first output step
  const int t_h   = (t_out > HALO) ? t_out - HALO : 0;  // exact for c<=2
  const int nh    = (t_out - t_h) / TS;                 // halo tiles (even)

  float* imem_p = out + ((size_t)b * (Tt + 1) + t_out + 1) * Ff + f0 + lane;
  float* spk_p =
      out + ((size_t)(Bb + b)) * (size_t)(Tt + 1) * Ff + (size_t)t_out * Ff +
      f0 + lane;

  if (c == 0) __builtin_nontemporal_store(0.0f, imem_p - Ff);  // imem[:,0,:]

  float A[TS], B[TS];  // statically indexed only (full unroll)
  float y = 0.0f, iA = 0.0f, iR = 0.0f, lastspk = 0.0f;

#define LOADT(buf, ti)                                        \
  {                                                           \
    const float* p = gx + (size_t)(t_h + (ti) * TS) * Ff;     \
    _Pragma("unroll") for (int j = 0; j < TS; ++j)            \
        buf[j] = p[(size_t)j * Ff];                           \
  }

#define HSTEP(xval)                                  \
  {                                                  \
    float x = (xval);                                \
    float inet = fmaf(x, KIN, -(iA + iR));           \
    y = fmaf(y, AZ, inet);                           \
    bool fired = y >= YTH;                           \
    y = fired ? 0.0f : y;                            \
    iA = fmaf(iA, CAHP, fired ? KA : 0.0f);          \
    iR = fmaf(iR, CREF, fired ? KR : 0.0f);          \
  }

#define FSTEP(xval)                                  \
  {                                                  \
    float x = (xval);                                \
    float inet = fmaf(x, KIN, -(iA + iR));           \
    y = fmaf(y, AZ, inet);                           \
    bool fired = y >= YTH;                           \
    y = fired ? 0.0f : y;                            \
    lastspk = fired ? 1.0f : 0.0f;                   \
    iA = fmaf(iA, CAHP, fired ? KA : 0.0f);          \
    iR = fmaf(iR, CREF, fired ? KR : 0.0f);          \
    __builtin_nontemporal_store(y, imem_p);          \
    __builtin_nontemporal_store(lastspk, spk_p);     \
    imem_p += Ff;                                    \
    spk_p += Ff;                                     \
  }

  // Prologue: tile 0 -> A.
  LOADT(A, 0);

  // Halo: state-only, double-buffered pairs. After loop, A holds tile nh.
  for (int i = 0; i < nh; i += 2) {
    LOADT(B, i + 1);
#pragma unroll
    for (int j = 0; j < TS; ++j) HSTEP(A[j]);
    LOADT(A, i + 2);
#pragma unroll
    for (int j = 0; j < TS; ++j) HSTEP(B[j]);
  }

  // Output tiles nh .. nh+OT-1.
  for (int i = nh; i < nh + OT; i += 2) {
    LOADT(B, i + 1);
#pragma unroll
    for (int j = 0; j < TS; ++j) FSTEP(A[j]);
    if (i + 2 < nh + OT) LOADT(A, i + 2);
#pragma unroll
    for (int j = 0; j < TS; ++j) FSTEP(B[j]);
  }

  // spikes[:, T, :] = fired_{T-1} (last chunk owns row T)
  if (c == CH - 1) __builtin_nontemporal_store(lastspk, spk_p);

#undef LOADT
#undef HSTEP
#undef FSTEP
}

extern "C" void kernel_launch(void* const* d_in, const int* in_sizes, int n_in,
                              void* d_out, int out_size, void* d_ws,
                              size_t ws_size, hipStream_t stream) {
  const float* in = (const float*)d_in[0];
  float* out = (float*)d_out;
  dim3 grid(CH * Bb * (Ff / 64));  // 2560 blocks, 1 wave each, ~10/CU
  dim3 block(64);
  hipLaunchKernelGGL(sa_scan, grid, block, 0, stream, in, out);
}